// Round 10
// baseline (1720.346 us; speedup 1.0000x reference)
//
#include <hip/hip_runtime.h>
#include <hip/hip_bf16.h>
#include <math.h>

#define BB 64      // batch
#define CC 64      // width/channels
#define SS 8192    // sequence
#define NMODE 256  // kept rfft modes
#define KK2 512    // 2*NMODE (re/im interleaved)

typedef __attribute__((ext_vector_type(8))) short short8;
typedef __attribute__((ext_vector_type(16))) float f32x16;

__device__ __forceinline__ float gelu_exact(float v) {
    return 0.5f * v * (1.0f + erff(v * 0.7071067811865476f));
}

__device__ __forceinline__ float b2f(ushort u) {
    return __uint_as_float(((unsigned int)u) << 16);
}
__device__ __forceinline__ ushort f2b(float v) {
    __hip_bfloat16 h = __float2bfloat16(v);  // RNE
    return *(ushort*)&h;
}
__device__ __forceinline__ void split2(float v, ushort& h, ushort& l) {
    h = f2b(v);
    l = f2b(v - b2f(h));
}

// ---------------- DFT basis tables (bf16 hi/lo pairs) ----------------
__global__ void build_T1(ushort* __restrict__ h, ushort* __restrict__ l) {
    int c = blockIdx.x;
    int n = blockIdx.y * 256 + threadIdx.x;
    int k = c >> 1;
    int m = (n * k) & (SS - 1);
    float th = (float)m * (6.283185307179586476925f / (float)SS);
    float s, co;
    sincosf(th, &s, &co);
    float v = (c & 1) ? -s : co;
    ushort hh, ll;
    split2(v, hh, ll);
    h[(size_t)c * SS + n] = hh;
    l[(size_t)c * SS + n] = ll;
}

__global__ void build_T2(ushort* __restrict__ h, ushort* __restrict__ l) {
    int n = blockIdx.x;
    int c = blockIdx.y * 256 + threadIdx.x;
    int k = c >> 1;
    int m = (n * k) & (SS - 1);
    float th = (float)m * (6.283185307179586476925f / (float)SS);
    float s, co;
    sincosf(th, &s, &co);
    float v = (c & 1) ? -s : co;
    ushort hh, ll;
    split2(v, hh, ll);
    h[(size_t)n * KK2 + c] = hh;
    l[(size_t)n * KK2 + c] = ll;
}

__global__ void zero_xf(float* __restrict__ p) {
    size_t i = ((size_t)blockIdx.x * 256 + threadIdx.x) * 4;
    *(float4*)&p[i] = make_float4(0.f, 0.f, 0.f, 0.f);
}

// ---------------- lifting layer (writes split x) ----------------
__global__ void lift_kernel(const float* __restrict__ u, const float* __restrict__ w0,
                            const float* __restrict__ b0, ushort* __restrict__ xh,
                            ushort* __restrict__ xl) {
    int n = blockIdx.x * 256 + threadIdx.x;
    int c = blockIdx.y;
    int b = blockIdx.z;
    float uv = u[b * SS + n];
    float g = (float)n * (1.0f / (float)(SS - 1));
    float v = uv * w0[c] + g * w0[CC + c] + b0[c];
    ushort hh, ll;
    split2(v, hh, ll);
    size_t idx = (size_t)(b * CC + c) * SS + n;
    xh[idx] = hh;
    xl[idx] = ll;
}

// ---------------- forward truncated DFT: split-bf16 32x32 MFMA GEMM ---------
// Xf[4096][512] += X[m][n] * T1[c][n]; K split 8 ways, atomic accumulate.
// XCD-aware 1-D grid decode (A-tile sharers land on one XCD). 2-barrier
// K=32 steps with register prefetch. launch_bounds(256,3): 3 blocks/CU.
__global__ __launch_bounds__(256, 3) void dft_mfma(const ushort* __restrict__ xh,
                                                   const ushort* __restrict__ xl,
                                                   const ushort* __restrict__ t1h,
                                                   const ushort* __restrict__ t1l,
                                                   float* __restrict__ Xf) {
    __shared__ __align__(16) ushort SM[16384];  // 32 KB pool
    ushort* As_h = SM;
    ushort* As_l = SM + 4096;
    ushort* Bs_h = SM + 8192;
    ushort* Bs_l = SM + 12288;
    const int t = threadIdx.x;
    const int L = blockIdx.x;  // 1024 blocks
    const int gq = L >> 5, j = L & 31;
    const int c0 = (j >> 3) * 128;                  // 4 c-tiles
    const int m0 = ((gq & 3) * 8 + (j & 7)) * 128;  // 32 m-tiles
    const int kz = (gq >> 2) * (SS / 8);            // 8 k-splits
    const int lane = t & 63, w = t >> 6;
    const int wm = (w >> 1) * 64, wn = (w & 1) * 64;
    const int l32 = lane & 31, lh = lane >> 5;
    const int sr = t >> 1, sh = (t & 1) * 16;
    const int g0 = (t & 1) * 2;
    const int d0 = ((g0 + 0) * 128 + sr) * 8;
    const int d1 = ((g0 + 1) * 128 + sr) * 8;

    f32x16 acc[2][2];
#pragma unroll
    for (int i = 0; i < 2; i++)
#pragma unroll
        for (int jj = 0; jj < 2; jj++) acc[i][jj] = (f32x16)0.f;

    const size_t arow = (size_t)(m0 + sr) * SS;
    const size_t brow = (size_t)(c0 + sr) * SS;
    const int kend = kz + SS / 8;

    short8 a0h, a1h, a0l, a1l, b0h, b1h, b0l, b1l;
    {
        const size_t ga = arow + kz + sh;
        const size_t gb = brow + kz + sh;
        a0h = *(const short8*)&xh[ga];
        a1h = *(const short8*)&xh[ga + 8];
        a0l = *(const short8*)&xl[ga];
        a1l = *(const short8*)&xl[ga + 8];
        b0h = *(const short8*)&t1h[gb];
        b1h = *(const short8*)&t1h[gb + 8];
        b0l = *(const short8*)&t1l[gb];
        b1l = *(const short8*)&t1l[gb + 8];
    }
    for (int kt = kz; kt < kend; kt += 32) {
        __syncthreads();
        *(short8*)&As_h[d0] = a0h;
        *(short8*)&As_h[d1] = a1h;
        *(short8*)&As_l[d0] = a0l;
        *(short8*)&As_l[d1] = a1l;
        *(short8*)&Bs_h[d0] = b0h;
        *(short8*)&Bs_h[d1] = b1h;
        *(short8*)&Bs_l[d0] = b0l;
        *(short8*)&Bs_l[d1] = b1l;
        __syncthreads();
        const int ktn = (kt + 32 < kend) ? kt + 32 : kz;
        const size_t ga = arow + ktn + sh;
        const size_t gb = brow + ktn + sh;
        a0h = *(const short8*)&xh[ga];
        a1h = *(const short8*)&xh[ga + 8];
        a0l = *(const short8*)&xl[ga];
        a1l = *(const short8*)&xl[ga + 8];
        b0h = *(const short8*)&t1h[gb];
        b1h = *(const short8*)&t1h[gb + 8];
        b0l = *(const short8*)&t1l[gb];
        b1l = *(const short8*)&t1l[gb + 8];
#pragma unroll
        for (int s2 = 0; s2 < 2; s2++) {
            const int kg = s2 * 2 + lh;
            short8 ah[2], al[2], bh2[2], bl2[2];
#pragma unroll
            for (int mt = 0; mt < 2; mt++) {
                int off = (kg * 128 + wm + mt * 32 + l32) * 8;
                ah[mt] = *(const short8*)&As_h[off];
                al[mt] = *(const short8*)&As_l[off];
            }
#pragma unroll
            for (int nt = 0; nt < 2; nt++) {
                int off = (kg * 128 + wn + nt * 32 + l32) * 8;
                bh2[nt] = *(const short8*)&Bs_h[off];
                bl2[nt] = *(const short8*)&Bs_l[off];
            }
#pragma unroll
            for (int nt = 0; nt < 2; nt++)
#pragma unroll
                for (int mt = 0; mt < 2; mt++) {
                    acc[mt][nt] = __builtin_amdgcn_mfma_f32_32x32x16_bf16(ah[mt], bh2[nt], acc[mt][nt], 0, 0, 0);
                    acc[mt][nt] = __builtin_amdgcn_mfma_f32_32x32x16_bf16(ah[mt], bl2[nt], acc[mt][nt], 0, 0, 0);
                    acc[mt][nt] = __builtin_amdgcn_mfma_f32_32x32x16_bf16(al[mt], bh2[nt], acc[mt][nt], 0, 0, 0);
                }
        }
    }
    // epilogue: C/D layout col=lane&31, row=(reg&3)+8*(reg>>2)+4*(lane>>5)
#pragma unroll
    for (int mt = 0; mt < 2; mt++)
#pragma unroll
        for (int nt = 0; nt < 2; nt++) {
            int col = c0 + wn + nt * 32 + l32;
#pragma unroll
            for (int reg = 0; reg < 16; reg++) {
                int row = m0 + wm + mt * 32 + (reg & 3) + 8 * (reg >> 2) + 4 * lh;
                atomicAdd(&Xf[(size_t)row * KK2 + col], acc[mt][nt][reg]);
            }
        }
}

// ---------------- mode mixing (fp32, 2x2 micro-tile, writes split om) --------
__global__ __launch_bounds__(256) void mode_mix(const float* __restrict__ Xf,
                                                const float* __restrict__ swr,
                                                const float* __restrict__ swi,
                                                ushort* __restrict__ omh,
                                                ushort* __restrict__ oml, int l) {
    int k = threadIdx.x;
    int bg = blockIdx.x * 2;
    int og = blockIdx.y * 2;
    float ar[2][2] = {}, ai[2][2] = {};
#pragma unroll 2
    for (int i = 0; i < CC; i++) {
        float2 x0 = *(const float2*)&Xf[((size_t)(bg + 0) * CC + i) * KK2 + 2 * k];
        float2 x1 = *(const float2*)&Xf[((size_t)(bg + 1) * CC + i) * KK2 + 2 * k];
        size_t wb = ((size_t)(l * CC + i) * CC + og) * NMODE + k;
        float wr0 = swr[wb], wi0 = swi[wb];
        float wr1 = swr[wb + NMODE], wi1 = swi[wb + NMODE];
        ar[0][0] += x0.x * wr0 - x0.y * wi0;
        ai[0][0] += x0.x * wi0 + x0.y * wr0;
        ar[0][1] += x0.x * wr1 - x0.y * wi1;
        ai[0][1] += x0.x * wi1 + x0.y * wr1;
        ar[1][0] += x1.x * wr0 - x1.y * wi0;
        ai[1][0] += x1.x * wi0 + x1.y * wr0;
        ar[1][1] += x1.x * wr1 - x1.y * wi1;
        ai[1][1] += x1.x * wi1 + x1.y * wr1;
    }
    float ck = (k == 0) ? (1.0f / (float)SS) : (2.0f / (float)SS);
#pragma unroll
    for (int b2 = 0; b2 < 2; b2++)
#pragma unroll
        for (int oo = 0; oo < 2; oo++) {
            float re = ar[b2][oo] * ck;
            float im = ai[b2][oo] * ck;
            ushort hr, lr2, hi2, li2;
            split2(re, hr, lr2);
            split2(im, hi2, li2);
            size_t base = ((size_t)(bg + b2) * CC + og + oo) * KK2 + 2 * k;
            *(ushort2*)&omh[base] = make_ushort2(hr, hi2);
            *(ushort2*)&oml[base] = make_ushort2(lr2, li2);
        }
}

// ---------------- inverse DFT + pointwise + bias + gelu (32x32 MFMA) --------
// Phase 1: K=512 modes, 2-barrier K=32 steps with register prefetch.
// Phase 2: K=64 channels via two LDS staging rounds (x-hi then x-lo tile,
// [128ch][128n] stride 136) -- NO parked registers, so launch_bounds(256,3)
// gives 3 blocks/CU (was 2: the parked fragments pushed VGPRs past 170).
__global__ __launch_bounds__(256, 3) void inv_mfma(const ushort* __restrict__ omh,
                                                   const ushort* __restrict__ oml,
                                                   const ushort* __restrict__ t2h,
                                                   const ushort* __restrict__ t2l,
                                                   const float* __restrict__ pww,
                                                   const float* __restrict__ pwb,
                                                   ushort* __restrict__ xh,
                                                   ushort* __restrict__ xl, int l,
                                                   int gel) {
    __shared__ __align__(16) ushort SM[17408];  // 34 KB (phase2 Xs[128][136])
    ushort* As_h = SM;
    ushort* As_l = SM + 4096;
    ushort* Bs_h = SM + 8192;
    ushort* Bs_l = SM + 12288;
    const int t = threadIdx.x;
    const int n0 = blockIdx.x * 128;
    const int row0 = blockIdx.y * 128;
    const int lane = t & 63, w = t >> 6;
    const int wm = (w >> 1) * 64, wn = (w & 1) * 64;
    const int l32 = lane & 31, lh = lane >> 5;
    const int sr = t >> 1, sh = (t & 1) * 16;
    const int g0 = (t & 1) * 2;
    const int d0 = ((g0 + 0) * 128 + sr) * 8;
    const int d1 = ((g0 + 1) * 128 + sr) * 8;

    f32x16 acc[2][2];
#pragma unroll
    for (int i = 0; i < 2; i++)
#pragma unroll
        for (int jj = 0; jj < 2; jj++) acc[i][jj] = (f32x16)0.f;

    const size_t arow = (size_t)(row0 + sr) * KK2;
    const size_t brow = (size_t)(n0 + sr) * KK2;

    short8 a0h, a1h, a0l, a1l, b0h, b1h, b0l, b1l;
    {
        const size_t ga = arow + sh;
        const size_t gb = brow + sh;
        a0h = *(const short8*)&omh[ga];
        a1h = *(const short8*)&omh[ga + 8];
        a0l = *(const short8*)&oml[ga];
        a1l = *(const short8*)&oml[ga + 8];
        b0h = *(const short8*)&t2h[gb];
        b1h = *(const short8*)&t2h[gb + 8];
        b0l = *(const short8*)&t2l[gb];
        b1l = *(const short8*)&t2l[gb + 8];
    }
    // phase 1: modes (16 steps of K=32)
    for (int kt = 0; kt < KK2; kt += 32) {
        __syncthreads();
        *(short8*)&As_h[d0] = a0h;
        *(short8*)&As_h[d1] = a1h;
        *(short8*)&As_l[d0] = a0l;
        *(short8*)&As_l[d1] = a1l;
        *(short8*)&Bs_h[d0] = b0h;
        *(short8*)&Bs_h[d1] = b1h;
        *(short8*)&Bs_l[d0] = b0l;
        *(short8*)&Bs_l[d1] = b1l;
        __syncthreads();
        const int ktn = (kt + 32 < KK2) ? kt + 32 : 0;
        const size_t ga = arow + ktn + sh;
        const size_t gb = brow + ktn + sh;
        a0h = *(const short8*)&omh[ga];
        a1h = *(const short8*)&omh[ga + 8];
        a0l = *(const short8*)&oml[ga];
        a1l = *(const short8*)&oml[ga + 8];
        b0h = *(const short8*)&t2h[gb];
        b1h = *(const short8*)&t2h[gb + 8];
        b0l = *(const short8*)&t2l[gb];
        b1l = *(const short8*)&t2l[gb + 8];
#pragma unroll
        for (int s2 = 0; s2 < 2; s2++) {
            const int kg = s2 * 2 + lh;
            short8 ah[2], al[2], bh2[2], bl2[2];
#pragma unroll
            for (int mt = 0; mt < 2; mt++) {
                int off = (kg * 128 + wm + mt * 32 + l32) * 8;
                ah[mt] = *(const short8*)&As_h[off];
                al[mt] = *(const short8*)&As_l[off];
            }
#pragma unroll
            for (int nt = 0; nt < 2; nt++) {
                int off = (kg * 128 + wn + nt * 32 + l32) * 8;
                bh2[nt] = *(const short8*)&Bs_h[off];
                bl2[nt] = *(const short8*)&Bs_l[off];
            }
#pragma unroll
            for (int nt = 0; nt < 2; nt++)
#pragma unroll
                for (int mt = 0; mt < 2; mt++) {
                    acc[mt][nt] = __builtin_amdgcn_mfma_f32_32x32x16_bf16(ah[mt], bh2[nt], acc[mt][nt], 0, 0, 0);
                    acc[mt][nt] = __builtin_amdgcn_mfma_f32_32x32x16_bf16(ah[mt], bl2[nt], acc[mt][nt], 0, 0, 0);
                    acc[mt][nt] = __builtin_amdgcn_mfma_f32_32x32x16_bf16(al[mt], bh2[nt], acc[mt][nt], 0, 0, 0);
                }
        }
    }
    // phase 2: pointwise conv via two LDS staging rounds (hi then lo).
    // Xs[128 chan-rows][136 stride] holds the block's own x tile; in-place
    // safe: reads complete before the epilogue writes.
    ushort* Xs = SM;
    const int xr = t >> 1, xc = (t & 1) * 64;
    const size_t xg = (size_t)(row0 + xr) * SS + n0 + xc;
#pragma unroll
    for (int s = 0; s < 2; s++) {
        const ushort* src = s ? xl : xh;
        short8 v[8];
#pragma unroll
        for (int q = 0; q < 8; q++) v[q] = *(const short8*)&src[xg + q * 8];
        __syncthreads();
#pragma unroll
        for (int q = 0; q < 8; q++) *(short8*)&Xs[xr * 136 + xc + q * 8] = v[q];
        __syncthreads();
#pragma unroll
        for (int ks = 0; ks < 4; ks++) {
            short8 pah[2], pal[2];
#pragma unroll
            for (int mt = 0; mt < 2; mt++) {
                int o = mt * 32 + l32;
                const float* pp = &pww[(size_t)(l * CC + o) * CC + ks * 16 + lh * 8];
                float4 pa = *(const float4*)pp;
                float4 pb = *(const float4*)(pp + 4);
                float pv[8] = {pa.x, pa.y, pa.z, pa.w, pb.x, pb.y, pb.z, pb.w};
#pragma unroll
                for (int e = 0; e < 8; e++) {
                    ushort h2, l2;
                    split2(pv[e], h2, l2);
                    pah[mt][e] = (short)h2;
                    pal[mt][e] = (short)l2;
                }
            }
#pragma unroll
            for (int nt = 0; nt < 2; nt++) {
                short8 bf;
                const int rbase = (wm + ks * 16 + lh * 8) * 136 + wn + nt * 32 + l32;
#pragma unroll
                for (int jj = 0; jj < 8; jj++) bf[jj] = (short)Xs[rbase + jj * 136];
#pragma unroll
                for (int mt = 0; mt < 2; mt++) {
                    acc[mt][nt] = __builtin_amdgcn_mfma_f32_32x32x16_bf16(pah[mt], bf, acc[mt][nt], 0, 0, 0);
                    if (s == 0)
                        acc[mt][nt] = __builtin_amdgcn_mfma_f32_32x32x16_bf16(pal[mt], bf, acc[mt][nt], 0, 0, 0);
                }
            }
        }
    }
    // epilogue: bias + gelu + split-store (in place; block owns rows x cols)
#pragma unroll
    for (int mt = 0; mt < 2; mt++)
#pragma unroll
        for (int reg = 0; reg < 16; reg++) {
            int roffs = (reg & 3) + 8 * (reg >> 2) + 4 * lh;
            int o = mt * 32 + roffs;
            float bias = pwb[l * CC + o];
            size_t rowg = (size_t)(row0 + wm + o) * SS;
#pragma unroll
            for (int nt = 0; nt < 2; nt++) {
                int n = n0 + wn + nt * 32 + l32;
                float v = acc[mt][nt][reg] + bias;
                if (gel) v = gelu_exact(v);
                ushort h2, l2;
                split2(v, h2, l2);
                xh[rowg + n] = h2;
                xl[rowg + n] = l2;
            }
        }
}

// ---------------- projection head ----------------
__global__ __launch_bounds__(256) void head_kernel(const ushort* __restrict__ xh,
                                                   const ushort* __restrict__ xl,
                                                   const float* __restrict__ w1,
                                                   const float* __restrict__ b1,
                                                   const float* __restrict__ w2,
                                                   const float* __restrict__ b2,
                                                   float* __restrict__ out) {
    __shared__ float Xs[64][64];
    __shared__ float W1s[64][128];
    __shared__ float part[4][64];
    int b = blockIdx.y;
    int n0 = blockIdx.x * 64;
    int tid = threadIdx.x;
    {
        int c = tid >> 2, nq = tid & 3;
        size_t gx = (size_t)(b * CC + c) * SS + n0 + nq * 16;
        short8 hA = *(const short8*)&xh[gx];
        short8 hB = *(const short8*)&xh[gx + 8];
        short8 lA = *(const short8*)&xl[gx];
        short8 lB = *(const short8*)&xl[gx + 8];
#pragma unroll
        for (int e = 0; e < 8; e++) {
            Xs[c][nq * 16 + e] = b2f((ushort)hA[e]) + b2f((ushort)lA[e]);
            Xs[c][nq * 16 + 8 + e] = b2f((ushort)hB[e]) + b2f((ushort)lB[e]);
        }
    }
    float* w1flat = &W1s[0][0];
#pragma unroll
    for (int q = 0; q < 8; q++) {
        int off = q * 1024 + tid * 4;
        *(float4*)&w1flat[off] = *(const float4*)&w1[off];
    }
    __syncthreads();
    int nn = tid & 63, jg = tid >> 6;
    float h[32];
#pragma unroll
    for (int jj = 0; jj < 32; jj++) h[jj] = b1[jg * 32 + jj];
    for (int c = 0; c < 64; c++) {
        float xv = Xs[c][nn];
#pragma unroll
        for (int jj = 0; jj < 32; jj++)
            h[jj] = fmaf(xv, W1s[c][jg * 32 + jj], h[jj]);
    }
    float p = 0.f;
#pragma unroll
    for (int jj = 0; jj < 32; jj++)
        p = fmaf(gelu_exact(h[jj]), w2[jg * 32 + jj], p);
    part[jg][nn] = p;
    __syncthreads();
    if (tid < 64) {
        float v = part[0][tid] + part[1][tid] + part[2][tid] + part[3][tid] + b2[0];
        out[b * SS + n0 + tid] = v;
    }
}

extern "C" void kernel_launch(void* const* d_in, const int* in_sizes, int n_in,
                              void* d_out, int out_size, void* d_ws, size_t ws_size,
                              hipStream_t stream) {
    (void)in_sizes; (void)n_in; (void)out_size; (void)ws_size;
    const float* u = (const float*)d_in[0];
    const float* fc0_w = (const float*)d_in[1];
    const float* fc0_b = (const float*)d_in[2];
    const float* sw_r = (const float*)d_in[3];
    const float* sw_i = (const float*)d_in[4];
    const float* pw_w = (const float*)d_in[5];
    const float* pw_b = (const float*)d_in[6];
    const float* fc1_w = (const float*)d_in[7];
    const float* fc1_b = (const float*)d_in[8];
    const float* fc2_w = (const float*)d_in[9];
    const float* fc2_b = (const float*)d_in[10];
    float* out = (float*)d_out;

    // workspace layout (total = 184,549,376 B)
    char* ws = (char*)d_ws;
    ushort* xh = (ushort*)ws;                  // 33,554,432 els
    ushort* xl = (ushort*)(ws + 67108864);     // 33,554,432
    ushort* t1h = (ushort*)(ws + 134217728);   // [512][8192]
    ushort* t1l = (ushort*)(ws + 142606336);
    ushort* t2h = (ushort*)(ws + 150994944);   // [8192][512]
    ushort* t2l = (ushort*)(ws + 159383552);
    ushort* omh = (ushort*)(ws + 167772160);   // [4096][512]
    ushort* oml = (ushort*)(ws + 171966464);
    float* Xf = (float*)(ws + 176160768);      // [4096][512] fp32

    build_T1<<<dim3(KK2, SS / 256), 256, 0, stream>>>(t1h, t1l);
    build_T2<<<dim3(SS, KK2 / 256), 256, 0, stream>>>(t2h, t2l);
    lift_kernel<<<dim3(SS / 256, CC, BB), 256, 0, stream>>>(u, fc0_w, fc0_b, xh, xl);

    for (int l = 0; l < 4; l++) {
        zero_xf<<<dim3(2048), 256, 0, stream>>>(Xf);
        dft_mfma<<<dim3(1024), 256, 0, stream>>>(xh, xl, t1h, t1l, Xf);
        mode_mix<<<dim3(BB / 2, CC / 2), 256, 0, stream>>>(Xf, sw_r, sw_i, omh, oml, l);
        inv_mfma<<<dim3(SS / 128, BB / 2), 256, 0, stream>>>(
            omh, oml, t2h, t2l, pw_w, pw_b, xh, xl, l, (l < 3) ? 1 : 0);
    }
    head_kernel<<<dim3(SS / 64, BB), 256, 0, stream>>>(xh, xl, fc1_w, fc1_b, fc2_w,
                                                       fc2_b, out);
}

// Round 11
// 1447.469 us; speedup vs baseline: 1.1885x; 1.1885x over previous
//
#include <hip/hip_runtime.h>
#include <hip/hip_bf16.h>
#include <math.h>

#define BB 64      // batch
#define CC 64      // width/channels
#define SS 8192    // sequence
#define HS 4096    // SS/2 (radix-2 half)
#define NMODE 256  // kept rfft modes
#define KK2 512    // 2*NMODE (re/im interleaved, permuted [even-k | odd-k])

typedef __attribute__((ext_vector_type(8))) short short8;
typedef __attribute__((ext_vector_type(16))) float f32x16;

__device__ __forceinline__ float gelu_exact(float v) {
    return 0.5f * v * (1.0f + erff(v * 0.7071067811865476f));
}
__device__ __forceinline__ float b2f(ushort u) {
    return __uint_as_float(((unsigned int)u) << 16);
}
__device__ __forceinline__ ushort f2b(float v) {
    __hip_bfloat16 h = __float2bfloat16(v);  // RNE
    return *(ushort*)&h;
}
__device__ __forceinline__ void split2(float v, ushort& h, ushort& l) {
    h = f2b(v);
    l = f2b(v - b2f(h));
}
// permuted col -> true frequency k
__device__ __forceinline__ int colk(int c) {
    return (c < 256) ? (c & ~1) : (((c - 256) & ~1) | 1);
}

// ---------------- DFT basis tables (bf16 hi/lo pairs, permuted cols) --------
// T1p[c][n<4096]: forward table (even-k rows pair with E, odd-k with O).
// T2r[n<4096][c]: inverse table. value = ri ? -sin(2πkn/S) : cos(2πkn/S).
__global__ void build_T1p(ushort* __restrict__ h, ushort* __restrict__ l) {
    int c = blockIdx.x;
    int n = blockIdx.y * 256 + threadIdx.x;
    int k = colk(c), ri = c & 1;
    int m = (n * k) & (SS - 1);
    float th = (float)m * (6.283185307179586476925f / (float)SS);
    float s, co;
    sincosf(th, &s, &co);
    float v = ri ? -s : co;
    ushort hh, ll;
    split2(v, hh, ll);
    h[(size_t)c * HS + n] = hh;
    l[(size_t)c * HS + n] = ll;
}

__global__ void build_T2r(ushort* __restrict__ h, ushort* __restrict__ l) {
    int n = blockIdx.x;
    int c = blockIdx.y * 256 + threadIdx.x;
    int k = colk(c), ri = c & 1;
    int m = (n * k) & (SS - 1);
    float th = (float)m * (6.283185307179586476925f / (float)SS);
    float s, co;
    sincosf(th, &s, &co);
    float v = ri ? -s : co;
    ushort hh, ll;
    split2(v, hh, ll);
    h[(size_t)n * KK2 + c] = hh;
    l[(size_t)n * KK2 + c] = ll;
}

__global__ void zero_xf(float* __restrict__ p) {
    size_t i = ((size_t)blockIdx.x * 256 + threadIdx.x) * 4;
    *(float4*)&p[i] = make_float4(0.f, 0.f, 0.f, 0.f);
}

// ---------------- lifting layer (writes split E/O directly) ----------------
__global__ void lift_kernel(const float* __restrict__ u, const float* __restrict__ w0,
                            const float* __restrict__ b0, ushort* __restrict__ Eh,
                            ushort* __restrict__ El, ushort* __restrict__ Oh,
                            ushort* __restrict__ Ol) {
    int n = blockIdx.x * 256 + threadIdx.x;  // 0..4095
    int c = blockIdx.y;
    int b = blockIdx.z;
    float g1 = (float)n * (1.0f / (float)(SS - 1));
    float g2 = (float)(n + HS) * (1.0f / (float)(SS - 1));
    float v1 = u[b * SS + n] * w0[c] + g1 * w0[CC + c] + b0[c];
    float v2 = u[b * SS + n + HS] * w0[c] + g2 * w0[CC + c] + b0[c];
    float E = v1 + v2, O = v1 - v2;
    ushort hh, ll;
    size_t idx = (size_t)(b * CC + c) * HS + n;
    split2(E, hh, ll);
    Eh[idx] = hh;
    El[idx] = ll;
    split2(O, hh, ll);
    Oh[idx] = hh;
    Ol[idx] = ll;
}

// ---------------- forward truncated DFT (radix-2): K=4096 MFMA GEMM --------
// Xf[4096][512p] += A[m][n<4096] * T1p[c][n]; A = E for c<256 (even k), O
// otherwise. K split 4 ways, atomic accumulate. XCD-aware decode; 2-barrier
// K=32 steps with register prefetch.
__global__ __launch_bounds__(256, 3) void dft_mfma(
    const ushort* __restrict__ Eh, const ushort* __restrict__ El,
    const ushort* __restrict__ Oh, const ushort* __restrict__ Ol,
    const ushort* __restrict__ t1h, const ushort* __restrict__ t1l,
    float* __restrict__ Xf) {
    __shared__ __align__(16) ushort SM[16384];  // 32 KB
    ushort* As_h = SM;
    ushort* As_l = SM + 4096;
    ushort* Bs_h = SM + 8192;
    ushort* Bs_l = SM + 12288;
    const int t = threadIdx.x;
    const int L = blockIdx.x;  // 512 blocks
    const int gq = L >> 5, j = L & 31;
    const int c0 = (j >> 3) * 128;
    const int m0 = ((gq & 3) * 8 + (j & 7)) * 128;
    const int kz = (gq >> 2) * 1024;  // 4 k-splits over K=4096
    const ushort* __restrict__ Ahp = (c0 < 256) ? Eh : Oh;
    const ushort* __restrict__ Alp = (c0 < 256) ? El : Ol;
    const int lane = t & 63, w = t >> 6;
    const int wm = (w >> 1) * 64, wn = (w & 1) * 64;
    const int l32 = lane & 31, lh = lane >> 5;
    const int sr = t >> 1, sh = (t & 1) * 16;
    const int g0 = (t & 1) * 2;
    const int d0 = ((g0 + 0) * 128 + sr) * 8;
    const int d1 = ((g0 + 1) * 128 + sr) * 8;

    f32x16 acc[2][2];
#pragma unroll
    for (int i = 0; i < 2; i++)
#pragma unroll
        for (int jj = 0; jj < 2; jj++) acc[i][jj] = (f32x16)0.f;

    const size_t arow = (size_t)(m0 + sr) * HS;
    const size_t brow = (size_t)(c0 + sr) * HS;
    const int kend = kz + 1024;

    short8 a0h, a1h, a0l, a1l, b0h, b1h, b0l, b1l;
    {
        const size_t ga = arow + kz + sh;
        const size_t gb = brow + kz + sh;
        a0h = *(const short8*)&Ahp[ga];
        a1h = *(const short8*)&Ahp[ga + 8];
        a0l = *(const short8*)&Alp[ga];
        a1l = *(const short8*)&Alp[ga + 8];
        b0h = *(const short8*)&t1h[gb];
        b1h = *(const short8*)&t1h[gb + 8];
        b0l = *(const short8*)&t1l[gb];
        b1l = *(const short8*)&t1l[gb + 8];
    }
    for (int kt = kz; kt < kend; kt += 32) {
        __syncthreads();
        *(short8*)&As_h[d0] = a0h;
        *(short8*)&As_h[d1] = a1h;
        *(short8*)&As_l[d0] = a0l;
        *(short8*)&As_l[d1] = a1l;
        *(short8*)&Bs_h[d0] = b0h;
        *(short8*)&Bs_h[d1] = b1h;
        *(short8*)&Bs_l[d0] = b0l;
        *(short8*)&Bs_l[d1] = b1l;
        __syncthreads();
        const int ktn = (kt + 32 < kend) ? kt + 32 : kz;
        const size_t ga = arow + ktn + sh;
        const size_t gb = brow + ktn + sh;
        a0h = *(const short8*)&Ahp[ga];
        a1h = *(const short8*)&Ahp[ga + 8];
        a0l = *(const short8*)&Alp[ga];
        a1l = *(const short8*)&Alp[ga + 8];
        b0h = *(const short8*)&t1h[gb];
        b1h = *(const short8*)&t1h[gb + 8];
        b0l = *(const short8*)&t1l[gb];
        b1l = *(const short8*)&t1l[gb + 8];
#pragma unroll
        for (int s2 = 0; s2 < 2; s2++) {
            const int kg = s2 * 2 + lh;
            short8 ah[2], al[2], bh2[2], bl2[2];
#pragma unroll
            for (int mt = 0; mt < 2; mt++) {
                int off = (kg * 128 + wm + mt * 32 + l32) * 8;
                ah[mt] = *(const short8*)&As_h[off];
                al[mt] = *(const short8*)&As_l[off];
            }
#pragma unroll
            for (int nt = 0; nt < 2; nt++) {
                int off = (kg * 128 + wn + nt * 32 + l32) * 8;
                bh2[nt] = *(const short8*)&Bs_h[off];
                bl2[nt] = *(const short8*)&Bs_l[off];
            }
#pragma unroll
            for (int nt = 0; nt < 2; nt++)
#pragma unroll
                for (int mt = 0; mt < 2; mt++) {
                    acc[mt][nt] = __builtin_amdgcn_mfma_f32_32x32x16_bf16(ah[mt], bh2[nt], acc[mt][nt], 0, 0, 0);
                    acc[mt][nt] = __builtin_amdgcn_mfma_f32_32x32x16_bf16(ah[mt], bl2[nt], acc[mt][nt], 0, 0, 0);
                    acc[mt][nt] = __builtin_amdgcn_mfma_f32_32x32x16_bf16(al[mt], bh2[nt], acc[mt][nt], 0, 0, 0);
                }
        }
    }
#pragma unroll
    for (int mt = 0; mt < 2; mt++)
#pragma unroll
        for (int nt = 0; nt < 2; nt++) {
            int col = c0 + wn + nt * 32 + l32;
#pragma unroll
            for (int reg = 0; reg < 16; reg++) {
                int row = m0 + wm + mt * 32 + (reg & 3) + 8 * (reg >> 2) + 4 * lh;
                atomicAdd(&Xf[(size_t)row * KK2 + col], acc[mt][nt][reg]);
            }
        }
}

// ---------------- mode mixing (permuted cols) --------------------------------
__global__ __launch_bounds__(256) void mode_mix(const float* __restrict__ Xf,
                                                const float* __restrict__ swr,
                                                const float* __restrict__ swi,
                                                ushort* __restrict__ omh,
                                                ushort* __restrict__ oml, int l) {
    int k = threadIdx.x;
    int bg = blockIdx.x * 2;
    int og = blockIdx.y * 2;
    const int cp = ((k & 1) << 8) | ((k >> 1) << 1);  // permuted re-col
    float ar[2][2] = {}, ai[2][2] = {};
#pragma unroll 2
    for (int i = 0; i < CC; i++) {
        float2 x0 = *(const float2*)&Xf[((size_t)(bg + 0) * CC + i) * KK2 + cp];
        float2 x1 = *(const float2*)&Xf[((size_t)(bg + 1) * CC + i) * KK2 + cp];
        size_t wb = ((size_t)(l * CC + i) * CC + og) * NMODE + k;
        float wr0 = swr[wb], wi0 = swi[wb];
        float wr1 = swr[wb + NMODE], wi1 = swi[wb + NMODE];
        ar[0][0] += x0.x * wr0 - x0.y * wi0;
        ai[0][0] += x0.x * wi0 + x0.y * wr0;
        ar[0][1] += x0.x * wr1 - x0.y * wi1;
        ai[0][1] += x0.x * wi1 + x0.y * wr1;
        ar[1][0] += x1.x * wr0 - x1.y * wi0;
        ai[1][0] += x1.x * wi0 + x1.y * wr0;
        ar[1][1] += x1.x * wr1 - x1.y * wi1;
        ai[1][1] += x1.x * wi1 + x1.y * wr1;
    }
    float ck = (k == 0) ? (1.0f / (float)SS) : (2.0f / (float)SS);
#pragma unroll
    for (int b2 = 0; b2 < 2; b2++)
#pragma unroll
        for (int oo = 0; oo < 2; oo++) {
            float re = ar[b2][oo] * ck;
            float im = ai[b2][oo] * ck;
            ushort hr, lr2, hi2, li2;
            split2(re, hr, lr2);
            split2(im, hi2, li2);
            size_t base = ((size_t)(bg + b2) * CC + og + oo) * KK2 + cp;
            *(ushort2*)&omh[base] = make_ushort2(hr, hi2);
            *(ushort2*)&oml[base] = make_ushort2(lr2, li2);
        }
}

// ---------------- inverse DFT (radix-2) + pointwise + gelu -------------------
// Block: 128 rows x 64 n-cols (n<4096). Phase 1: P (even-k, K=256) and Q
// (odd-k, K=256) accumulated separately; butterfly u=P+Q (y[n]), v=P-Q
// (y[n+4096]). Phase 2: pw*x = (pw/2)E ± (pw/2)O, 4 staging rounds.
// Epilogue: bias+gelu both, write E,O (split) -- next layer's input.
__global__ __launch_bounds__(256, 3) void inv_mfma(
    const ushort* __restrict__ omh, const ushort* __restrict__ oml,
    const ushort* __restrict__ t2h, const ushort* __restrict__ t2l,
    const float* __restrict__ pww, const float* __restrict__ pwb,
    ushort* __restrict__ Eh, ushort* __restrict__ El,
    ushort* __restrict__ Oh, ushort* __restrict__ Ol, int l, int gel) {
    __shared__ __align__(16) ushort SM[12288];  // 24 KB
    ushort* As_h = SM;
    ushort* As_l = SM + 4096;
    ushort* Bs_h = SM + 8192;
    ushort* Bs_l = SM + 10240;
    const int t = threadIdx.x;
    const int n0 = blockIdx.x * 64;    // n < 4096
    const int row0 = blockIdx.y * 128; // 2 batches x 64 out-ch
    const int lane = t & 63, w = t >> 6;
    const int wm = (w >> 1) * 64, wn = (w & 1) * 32;
    const int l32 = lane & 31, lh = lane >> 5;
    const int sr = t >> 1, sh = (t & 1) * 16;
    const int g0 = (t & 1) * 2;
    const int dA0 = ((g0 + 0) * 128 + sr) * 8;
    const int dA1 = ((g0 + 1) * 128 + sr) * 8;
    const int srB = (t >> 1) & 63;
    const int dB0 = ((g0 + 0) * 64 + srB) * 8;
    const int dB1 = ((g0 + 1) * 64 + srB) * 8;
    const bool doB = t < 128;

    f32x16 aP[2], aQ[2];
#pragma unroll
    for (int i = 0; i < 2; i++) {
        aP[i] = (f32x16)0.f;
        aQ[i] = (f32x16)0.f;
    }

    const size_t arow = (size_t)(row0 + sr) * KK2;
    const size_t brow = (size_t)(n0 + srB) * KK2;

    short8 a0h, a1h, a0l, a1l, b0h, b1h, b0l, b1l;
    {
        const size_t ga = arow + sh;
        a0h = *(const short8*)&omh[ga];
        a1h = *(const short8*)&omh[ga + 8];
        a0l = *(const short8*)&oml[ga];
        a1l = *(const short8*)&oml[ga + 8];
        if (doB) {
            const size_t gb = brow + sh;
            b0h = *(const short8*)&t2h[gb];
            b1h = *(const short8*)&t2h[gb + 8];
            b0l = *(const short8*)&t2l[gb];
            b1l = *(const short8*)&t2l[gb + 8];
        }
    }
    // phase 1: halves (P: cols 0..255, Q: 256..511), 8 K=32 steps each
#pragma unroll
    for (int half = 0; half < 2; half++) {
        f32x16* acc = half ? aQ : aP;
        for (int hs8 = 0; hs8 < 8; hs8++) {
            const int hs = half * 8 + hs8;
            __syncthreads();
            *(short8*)&As_h[dA0] = a0h;
            *(short8*)&As_h[dA1] = a1h;
            *(short8*)&As_l[dA0] = a0l;
            *(short8*)&As_l[dA1] = a1l;
            if (doB) {
                *(short8*)&Bs_h[dB0] = b0h;
                *(short8*)&Bs_h[dB1] = b1h;
                *(short8*)&Bs_l[dB0] = b0l;
                *(short8*)&Bs_l[dB1] = b1l;
            }
            __syncthreads();
            const int ktn = (hs + 1 < 16) ? (hs + 1) * 32 : 0;
            const size_t ga = arow + ktn + sh;
            a0h = *(const short8*)&omh[ga];
            a1h = *(const short8*)&omh[ga + 8];
            a0l = *(const short8*)&oml[ga];
            a1l = *(const short8*)&oml[ga + 8];
            if (doB) {
                const size_t gb = brow + ktn + sh;
                b0h = *(const short8*)&t2h[gb];
                b1h = *(const short8*)&t2h[gb + 8];
                b0l = *(const short8*)&t2l[gb];
                b1l = *(const short8*)&t2l[gb + 8];
            }
#pragma unroll
            for (int s2 = 0; s2 < 2; s2++) {
                const int kg = s2 * 2 + lh;
                short8 ah[2], al[2];
#pragma unroll
                for (int mt = 0; mt < 2; mt++) {
                    int off = (kg * 128 + wm + mt * 32 + l32) * 8;
                    ah[mt] = *(const short8*)&As_h[off];
                    al[mt] = *(const short8*)&As_l[off];
                }
                const int offb = (kg * 64 + wn + l32) * 8;
                short8 bh = *(const short8*)&Bs_h[offb];
                short8 bl = *(const short8*)&Bs_l[offb];
#pragma unroll
                for (int mt = 0; mt < 2; mt++) {
                    acc[mt] = __builtin_amdgcn_mfma_f32_32x32x16_bf16(ah[mt], bh, acc[mt], 0, 0, 0);
                    acc[mt] = __builtin_amdgcn_mfma_f32_32x32x16_bf16(ah[mt], bl, acc[mt], 0, 0, 0);
                    acc[mt] = __builtin_amdgcn_mfma_f32_32x32x16_bf16(al[mt], bh, acc[mt], 0, 0, 0);
                }
            }
        }
    }
    // butterfly: aP := u = P+Q (y[n]), aQ := v = P-Q (y[n+HS])
#pragma unroll
    for (int mt = 0; mt < 2; mt++) {
        f32x16 p = aP[mt];
        aP[mt] = p + aQ[mt];
        aQ[mt] = p - aQ[mt];
    }
    // phase 2: pointwise. 4 rounds: Eh, El, Oh, Ol tiles (2 bs x 64ch x 64n).
    const int bsw = w >> 1;
    const int xbs = t >> 7, xi = (t >> 1) & 63, xseg = (t & 1) * 32;
    const size_t xg = (size_t)(row0 + xbs * 64 + xi) * HS + n0 + xseg;
    const ushort* const srcs[4] = {Eh, El, Oh, Ol};
#pragma unroll
    for (int r = 0; r < 4; r++) {
        const ushort* src = srcs[r];
        const bool isO = (r >= 2), isHi = !(r & 1);
        short8 v0 = *(const short8*)&src[xg];
        short8 v1 = *(const short8*)&src[xg + 8];
        short8 v2 = *(const short8*)&src[xg + 16];
        short8 v3 = *(const short8*)&src[xg + 24];
        __syncthreads();
        {
            ushort* d = &SM[xbs * 4608 + xi * 72 + xseg];
            *(short8*)d = v0;
            *(short8*)(d + 8) = v1;
            *(short8*)(d + 16) = v2;
            *(short8*)(d + 24) = v3;
        }
        __syncthreads();
#pragma unroll
        for (int ks = 0; ks < 4; ks++) {
            short8 pah[2], pal[2], pnh[2], pnl[2];
#pragma unroll
            for (int mt = 0; mt < 2; mt++) {
                int o = mt * 32 + l32;
                const float* pp = &pww[(size_t)(l * CC + o) * CC + ks * 16 + lh * 8];
                float4 pa = *(const float4*)pp;
                float4 pb = *(const float4*)(pp + 4);
                float pv[8] = {pa.x, pa.y, pa.z, pa.w, pb.x, pb.y, pb.z, pb.w};
#pragma unroll
                for (int e = 0; e < 8; e++) {
                    ushort h2, l2;
                    split2(0.5f * pv[e], h2, l2);
                    pah[mt][e] = (short)h2;
                    pal[mt][e] = (short)l2;
                    pnh[mt][e] = (short)(h2 ^ 0x8000);
                    pnl[mt][e] = (short)(l2 ^ 0x8000);
                }
            }
            short8 bf;
            const int rb = bsw * 4608 + (ks * 16 + lh * 8) * 72 + wn + l32;
#pragma unroll
            for (int jj = 0; jj < 8; jj++) bf[jj] = (short)SM[rb + jj * 72];
#pragma unroll
            for (int mt = 0; mt < 2; mt++) {
                aP[mt] = __builtin_amdgcn_mfma_f32_32x32x16_bf16(pah[mt], bf, aP[mt], 0, 0, 0);
                aQ[mt] = __builtin_amdgcn_mfma_f32_32x32x16_bf16(isO ? pnh[mt] : pah[mt], bf, aQ[mt], 0, 0, 0);
                if (isHi) {
                    aP[mt] = __builtin_amdgcn_mfma_f32_32x32x16_bf16(pal[mt], bf, aP[mt], 0, 0, 0);
                    aQ[mt] = __builtin_amdgcn_mfma_f32_32x32x16_bf16(isO ? pnl[mt] : pal[mt], bf, aQ[mt], 0, 0, 0);
                }
            }
        }
    }
    // epilogue: bias + gelu on both halves, butterfly to E/O, split-store
#pragma unroll
    for (int mt = 0; mt < 2; mt++)
#pragma unroll
        for (int reg = 0; reg < 16; reg++) {
            int roffs = (reg & 3) + 8 * (reg >> 2) + 4 * lh;
            int o = mt * 32 + roffs;
            float bias = pwb[l * CC + o];
            float uu = aP[mt][reg] + bias;
            float vv = aQ[mt][reg] + bias;
            if (gel) {
                uu = gelu_exact(uu);
                vv = gelu_exact(vv);
            }
            float EE = uu + vv, OO = uu - vv;
            ushort h2, l2;
            size_t gg = (size_t)(row0 + wm + mt * 32 + roffs) * HS + n0 + wn + l32;
            split2(EE, h2, l2);
            Eh[gg] = h2;
            El[gg] = l2;
            split2(OO, h2, l2);
            Oh[gg] = h2;
            Ol[gg] = l2;
        }
}

// ---------------- projection head (reconstruct x = (E±O)/2) -----------------
__global__ __launch_bounds__(256) void head_kernel(
    const ushort* __restrict__ Eh, const ushort* __restrict__ El,
    const ushort* __restrict__ Oh, const ushort* __restrict__ Ol,
    const float* __restrict__ w1, const float* __restrict__ b1,
    const float* __restrict__ w2, const float* __restrict__ b2,
    float* __restrict__ out) {
    __shared__ float Xs[64][64];
    __shared__ float W1s[64][128];
    __shared__ float part[4][64];
    int b = blockIdx.y;
    int n0 = blockIdx.x * 64;
    int tid = threadIdx.x;
    const float sgn = (n0 < HS) ? 1.0f : -1.0f;
    const int nc = n0 & (HS - 1);
    {
        int c = tid >> 2, nq = tid & 3;
        size_t gx = (size_t)(b * CC + c) * HS + nc + nq * 16;
        short8 eh0 = *(const short8*)&Eh[gx], eh1 = *(const short8*)&Eh[gx + 8];
        short8 el0 = *(const short8*)&El[gx], el1 = *(const short8*)&El[gx + 8];
        short8 oh0 = *(const short8*)&Oh[gx], oh1 = *(const short8*)&Oh[gx + 8];
        short8 ol0 = *(const short8*)&Ol[gx], ol1 = *(const short8*)&Ol[gx + 8];
#pragma unroll
        for (int e = 0; e < 8; e++) {
            float e0 = b2f((ushort)eh0[e]) + b2f((ushort)el0[e]);
            float o0 = b2f((ushort)oh0[e]) + b2f((ushort)ol0[e]);
            float e1 = b2f((ushort)eh1[e]) + b2f((ushort)el1[e]);
            float o1 = b2f((ushort)oh1[e]) + b2f((ushort)ol1[e]);
            Xs[c][nq * 16 + e] = 0.5f * (e0 + sgn * o0);
            Xs[c][nq * 16 + 8 + e] = 0.5f * (e1 + sgn * o1);
        }
    }
    float* w1flat = &W1s[0][0];
#pragma unroll
    for (int q = 0; q < 8; q++) {
        int off = q * 1024 + tid * 4;
        *(float4*)&w1flat[off] = *(const float4*)&w1[off];
    }
    __syncthreads();
    int nn = tid & 63, jg = tid >> 6;
    float h[32];
#pragma unroll
    for (int jj = 0; jj < 32; jj++) h[jj] = b1[jg * 32 + jj];
    for (int c = 0; c < 64; c++) {
        float xv = Xs[c][nn];
#pragma unroll
        for (int jj = 0; jj < 32; jj++)
            h[jj] = fmaf(xv, W1s[c][jg * 32 + jj], h[jj]);
    }
    float p = 0.f;
#pragma unroll
    for (int jj = 0; jj < 32; jj++)
        p = fmaf(gelu_exact(h[jj]), w2[jg * 32 + jj], p);
    part[jg][nn] = p;
    __syncthreads();
    if (tid < 64) {
        float v = part[0][tid] + part[1][tid] + part[2][tid] + part[3][tid] + b2[0];
        out[b * SS + n0 + tid] = v;
    }
}

extern "C" void kernel_launch(void* const* d_in, const int* in_sizes, int n_in,
                              void* d_out, int out_size, void* d_ws, size_t ws_size,
                              hipStream_t stream) {
    (void)in_sizes; (void)n_in; (void)out_size; (void)ws_size;
    const float* u = (const float*)d_in[0];
    const float* fc0_w = (const float*)d_in[1];
    const float* fc0_b = (const float*)d_in[2];
    const float* sw_r = (const float*)d_in[3];
    const float* sw_i = (const float*)d_in[4];
    const float* pw_w = (const float*)d_in[5];
    const float* pw_b = (const float*)d_in[6];
    const float* fc1_w = (const float*)d_in[7];
    const float* fc1_b = (const float*)d_in[8];
    const float* fc2_w = (const float*)d_in[9];
    const float* fc2_b = (const float*)d_in[10];
    float* out = (float*)d_out;

    // workspace layout (total = 167,772,160 B)
    char* ws = (char*)d_ws;
    ushort* Eh = (ushort*)ws;                  // [4096][4096]
    ushort* El = (ushort*)(ws + 33554432);
    ushort* Oh = (ushort*)(ws + 67108864);
    ushort* Ol = (ushort*)(ws + 100663296);
    ushort* t1h = (ushort*)(ws + 134217728);   // [512][4096]
    ushort* t1l = (ushort*)(ws + 138412032);
    ushort* t2h = (ushort*)(ws + 142606336);   // [4096][512]
    ushort* t2l = (ushort*)(ws + 146800640);
    ushort* omh = (ushort*)(ws + 150994944);   // [4096][512]
    ushort* oml = (ushort*)(ws + 155189248);
    float* Xf = (float*)(ws + 159383552);      // [4096][512] fp32

    build_T1p<<<dim3(KK2, HS / 256), 256, 0, stream>>>(t1h, t1l);
    build_T2r<<<dim3(HS, KK2 / 256), 256, 0, stream>>>(t2h, t2l);
    lift_kernel<<<dim3(HS / 256, CC, BB), 256, 0, stream>>>(u, fc0_w, fc0_b, Eh, El,
                                                            Oh, Ol);
    for (int l = 0; l < 4; l++) {
        zero_xf<<<dim3(2048), 256, 0, stream>>>(Xf);
        dft_mfma<<<dim3(512), 256, 0, stream>>>(Eh, El, Oh, Ol, t1h, t1l, Xf);
        mode_mix<<<dim3(BB / 2, CC / 2), 256, 0, stream>>>(Xf, sw_r, sw_i, omh, oml, l);
        inv_mfma<<<dim3(HS / 64, 32), 256, 0, stream>>>(
            omh, oml, t2h, t2l, pw_w, pw_b, Eh, El, Oh, Ol, l, (l < 3) ? 1 : 0);
    }
    head_kernel<<<dim3(SS / 64, BB), 256, 0, stream>>>(Eh, El, Oh, Ol, fc1_w, fc1_b,
                                                       fc2_w, fc2_b, out);
}